// Round 4
// baseline (2224.971 us; speedup 1.0000x reference)
//
#include <hip/hip_runtime.h>
#include <hip/hip_bf16.h>
#include <hip/hip_fp16.h>

#define BT 16384
#define F 32
#define H 256
#define FH 8192

typedef _Float16 half8 __attribute__((ext_vector_type(8)));
typedef float float4v __attribute__((ext_vector_type(4)));

#define GLD_LDS(gsrc, ldst) \
    __builtin_amdgcn_global_load_lds( \
        (const __attribute__((address_space(1))) void*)(gsrc), \
        (__attribute__((address_space(3))) void*)(ldst), 16, 0, 0)

// ---------------------------------------------------------------------------
// Prep: transpose w2/wg/wf (F,H_contr,H_out) fp32 -> [f][n_out][h_contr] fp16
// ---------------------------------------------------------------------------
__global__ __launch_bounds__(256) void transpose_w_kernel(
    const float* __restrict__ w2, const float* __restrict__ wg,
    const float* __restrict__ wf, _Float16* __restrict__ wt)
{
    __shared__ float tile[64][65];
    int bid = blockIdx.x;
    int tens = bid >> 9, rem = bid & 511;
    int f = rem >> 4, tl = rem & 15;
    int hb = (tl >> 2) * 64, nb = (tl & 3) * 64;
    const float* src = (tens == 0 ? w2 : (tens == 1 ? wg : wf)) + f * 65536;
    _Float16* dst = wt + (size_t)tens * 2097152 + f * 65536;
    int lane = threadIdx.x & 63, w = threadIdx.x >> 6;
    for (int i = 0; i < 16; ++i) {
        int r = i * 4 + w;
        tile[r][lane] = src[(hb + r) * 256 + nb + lane];
    }
    __syncthreads();
    for (int i = 0; i < 16; ++i) {
        int c = i * 4 + w;
        dst[(nb + c) * 256 + hb + lane] = (_Float16)tile[lane][c];
    }
}

// ---------------------------------------------------------------------------
// Prep: Wcat[n][k] fp16, n<256 from sw1 (8192,256), n in [256,288) from ssw
// ---------------------------------------------------------------------------
__global__ __launch_bounds__(256) void transpose_s_kernel(
    const float* __restrict__ sw1, const float* __restrict__ ssw,
    _Float16* __restrict__ wcat)
{
    __shared__ float tile[64][65];
    int bid = blockIdx.x;
    int lane = threadIdx.x & 63, w = threadIdx.x >> 6;
    if (bid < 512) {
        int k0 = (bid >> 2) * 64, n0 = (bid & 3) * 64;
        for (int i = 0; i < 16; ++i) {
            int r = i * 4 + w;
            tile[r][lane] = sw1[(size_t)(k0 + r) * 256 + n0 + lane];
        }
        __syncthreads();
        for (int i = 0; i < 16; ++i) {
            int c = i * 4 + w;
            wcat[(size_t)(n0 + c) * FH + k0 + lane] = (_Float16)tile[lane][c];
        }
    } else {
        int k0 = (bid - 512) * 64;
        int t = threadIdx.x;
        for (int i = 0; i < 8; ++i) {
            int idx = t + i * 256;
            int r = idx >> 5, cc = idx & 31;
            tile[r][cc] = ssw[(size_t)(k0 + r) * 32 + cc];
        }
        __syncthreads();
        for (int i = 0; i < 8; ++i) {
            int idx = t + i * 256;
            int c = idx >> 6, rr = idx & 63;
            wcat[(size_t)(256 + c) * FH + k0 + rr] = (_Float16)tile[rr][c];
        }
    }
}

// ---------------------------------------------------------------------------
// grn gemm stage with global_load_lds + XOR swizzle.
// Bs layout: 256 rows x 64 fp16 (unpadded). Row n, LDS chunk-pos cp (16B units)
// holds source chunk c = cp ^ (n&7). Fragment read for k-chunk (4*ks+q) of row
// n reads cp = (4*ks+q) ^ (n&7).
// ---------------------------------------------------------------------------
__device__ __forceinline__ void gemm_stage(
    const _Float16* __restrict__ Bsrc,   // weight slice for this f: [n][k], k contig
    const _Float16* As, _Float16* Bs,
    int t, int wv, int ln, int q, float4v acc[2][4])
{
    for (int kc = 0; kc < 4; ++kc) {
        __syncthreads();
#pragma unroll
        for (int it = 0; it < 8; ++it) {
            int s = it * 256 + t;          // LDS slot (wave-contiguous)
            int n = s >> 3;
            int c = (s & 7) ^ (n & 7);     // source chunk (xor swizzle)
            GLD_LDS(Bsrc + n * 256 + kc * 64 + c * 8, Bs + s * 8);
        }
        __syncthreads();
        for (int ks = 0; ks < 2; ++ks) {
            int kb = kc * 64 + ks * 32 + q * 8;
            half8 a0 = *(const half8*)&As[(0 + ln) * 264 + kb];
            half8 a1 = *(const half8*)&As[(16 + ln) * 264 + kb];
#pragma unroll
            for (int nt = 0; nt < 4; ++nt) {
                int n = wv * 64 + nt * 16 + ln;
                int cp = (ks * 4 + q) ^ (n & 7);
                half8 b8 = *(const half8*)&Bs[n * 64 + cp * 8];
                acc[0][nt] = __builtin_amdgcn_mfma_f32_16x16x32_f16(a0, b8, acc[0][nt], 0, 0, 0);
                acc[1][nt] = __builtin_amdgcn_mfma_f32_16x16x32_f16(a1, b8, acc[1][nt], 0, 0, 0);
            }
        }
    }
}

// ---------------------------------------------------------------------------
// Fused per-feature GRN: 3 GEMMs (K=256) + GLU + residual + LayerNorm
// One block = 32 tokens x one feature f. stacked written fp16 (chunk-local).
// ---------------------------------------------------------------------------
__global__ __launch_bounds__(256) void grn_kernel(
    const float* __restrict__ x, const float* __restrict__ w1, const float* __restrict__ b1,
    const float* __restrict__ b2, const float* __restrict__ bg, const float* __restrict__ bfv_,
    const float* __restrict__ gamma, const float* __restrict__ beta,
    const float* __restrict__ wsk, const float* __restrict__ bsk,
    const _Float16* __restrict__ w2t, const _Float16* __restrict__ wgt,
    const _Float16* __restrict__ wft, _Float16* __restrict__ stacked, int tok_base)
{
    __shared__ __align__(16) char smem[53248];
    _Float16* As = (_Float16*)smem;                     // 32 x 264 fp16
    float* xs = (float*)(smem + 16896);                 // 32
    _Float16* Bs = (_Float16*)(smem + 17024);           // 256 x 64 fp16 (swizzled)
    float* ys = (float*)(smem + 17024);                 // 32 x 265 f32 (alias Bs)
    float* red = (float*)(smem + 17024 + 33920);        // 512
    float* mv = (float*)(smem + 17024 + 33920 + 2048);  // 64

    const int f = blockIdx.y;
    const int tok0 = blockIdx.x * 32;                   // chunk-local
    const int t = threadIdx.x;
    const int wv = t >> 6;
    const int ln = t & 15;
    const int q = (t & 63) >> 4;

    if (t < 32) xs[t] = x[(size_t)(tok_base + tok0 + t) * F + f];
    __syncthreads();

    // A = elu(x * w1 + b1), fp16 into LDS (32 x 256, stride 264)
    {
        float w1v = w1[f * H + t];
        float b1v = b1[f * H + t];
#pragma unroll 4
        for (int i = 0; i < 32; ++i) {
            float z = xs[i] * w1v + b1v;
            float e = z > 0.f ? z : (expf(z) - 1.f);
            As[i * 264 + t] = (_Float16)e;
        }
    }
    // stage 1: h2 = A @ w2 + b2
    float4v acc1[2][4];
#pragma unroll
    for (int mt = 0; mt < 2; ++mt)
#pragma unroll
        for (int nt = 0; nt < 4; ++nt)
#pragma unroll
            for (int r = 0; r < 4; ++r) acc1[mt][nt][r] = 0.f;
    gemm_stage(w2t + (size_t)f * 65536, As, Bs, t, wv, ln, q, acc1);

    __syncthreads();  // all stage-1 MFMA reads of As done
    {
        const float* b2f = b2 + f * H;
#pragma unroll
        for (int mt = 0; mt < 2; ++mt)
#pragma unroll
            for (int nt = 0; nt < 4; ++nt) {
                int n = wv * 64 + nt * 16 + ln;
                float b2v = b2f[n];
#pragma unroll
                for (int r = 0; r < 4; ++r) {
                    int m = mt * 16 + q * 4 + r;
                    As[m * 264 + n] = (_Float16)(acc1[mt][nt][r] + b2v);
                }
            }
    }
    // stage 2: Cg = h2 @ wg, Cf = h2 @ wf (sequential, reuse Bs)
    float4v accG[2][4], accF[2][4];
#pragma unroll
    for (int mt = 0; mt < 2; ++mt)
#pragma unroll
        for (int nt = 0; nt < 4; ++nt)
#pragma unroll
            for (int r = 0; r < 4; ++r) { accG[mt][nt][r] = 0.f; accF[mt][nt][r] = 0.f; }
    gemm_stage(wgt + (size_t)f * 65536, As, Bs, t, wv, ln, q, accG);
    gemm_stage(wft + (size_t)f * 65536, As, Bs, t, wv, ln, q, accF);

    // epilogue: y = sigmoid(Cg+bg)*(Cf+bf) + x*ws + bs, into LDS f32
    __syncthreads();
    {
        const float* bgf = bg + f * H;
        const float* bff = bfv_ + f * H;
        const float* wsf = wsk + f * H;
        const float* bsf = bsk + f * H;
#pragma unroll
        for (int mt = 0; mt < 2; ++mt)
#pragma unroll
            for (int nt = 0; nt < 4; ++nt) {
                int n = wv * 64 + nt * 16 + ln;
                float bgv = bgf[n], bfv = bff[n], wsv = wsf[n], bsv = bsf[n];
#pragma unroll
                for (int r = 0; r < 4; ++r) {
                    int m = mt * 16 + q * 4 + r;
                    float cg = accG[mt][nt][r] + bgv;
                    float cf = accF[mt][nt][r] + bfv;
                    float sig = 1.f / (1.f + expf(-cg));
                    ys[m * 265 + n] = sig * cf + xs[m] * wsv + bsv;
                }
            }
    }
    __syncthreads();
    // LayerNorm over H=256 per row
    {
        int row = t >> 3, seg = t & 7;
        float s1 = 0.f, s2 = 0.f;
#pragma unroll 8
        for (int j = 0; j < 32; ++j) {
            float v = ys[row * 265 + seg * 32 + j];
            s1 += v; s2 += v * v;
        }
        red[t] = s1; red[256 + t] = s2;
    }
    __syncthreads();
    if (t < 32) {
        float a = 0.f, b = 0.f;
        for (int s = 0; s < 8; ++s) { a += red[t * 8 + s]; b += red[256 + t * 8 + s]; }
        float mean = a * (1.f / 256.f);
        float var = b * (1.f / 256.f) - mean * mean;
        mv[t] = mean;
        mv[32 + t] = rsqrtf(var + 1e-5f);
    }
    __syncthreads();
    {
        float gv = gamma[f * H + t], bv = beta[f * H + t];
        for (int i = 0; i < 32; ++i) {
            float v = (ys[i * 265 + t] - mv[i]) * mv[32 + i] * gv + bv;
            stacked[(size_t)(tok0 + i) * FH + f * H + t] = (_Float16)v;
        }
    }
}

// ---------------------------------------------------------------------------
// Selection GEMM, split-K: grid (C/32 m-tiles, 8 k-slices). Each block:
// 32 tokens x N=288 x K=1024 -> plain-stores fp32 partial to
// part[kslice][token][288] (deterministic; no atomics).
// ---------------------------------------------------------------------------
__global__ __launch_bounds__(256) void sel_gemm_kernel(
    const _Float16* __restrict__ stacked, const _Float16* __restrict__ wcat,
    float* __restrict__ part, int Ctok)
{
    __shared__ __align__(16) _Float16 As2[32 * 64];     // 4 KB
    __shared__ __align__(16) _Float16 Bs2[288 * 64];    // 36 KB
    const int t = threadIdx.x;
    const int wv = t >> 6, ln = t & 15, q = (t & 63) >> 4;
    const int tok0 = blockIdx.x * 32;                   // chunk-local
    const int kb = blockIdx.y;                          // k-slice 0..7
    const int NT = (wv < 2) ? 5 : 4;                    // n-tiles per wave (18 total)
    float4v acc[2][5];
#pragma unroll
    for (int mt = 0; mt < 2; ++mt)
#pragma unroll
        for (int i = 0; i < 5; ++i)
#pragma unroll
            for (int r = 0; r < 4; ++r) acc[mt][i][r] = 0.f;

    for (int kc = 0; kc < 16; ++kc) {
        const int k0 = (kb * 16 + kc) * 64;
        __syncthreads();
        {
            // A: 32 rows x 8 chunks = 256 slots (1/thread)
            int n = t >> 3;
            int c = (t & 7) ^ (n & 7);
            GLD_LDS(stacked + (size_t)(tok0 + n) * FH + k0 + c * 8, As2 + t * 8);
            // B: 288 rows x 8 chunks = 2304 slots (9/thread)
#pragma unroll
            for (int i = 0; i < 9; ++i) {
                int s = t + i * 256;
                int nb = s >> 3;
                int cb = (s & 7) ^ (nb & 7);
                GLD_LDS(wcat + (size_t)nb * FH + k0 + cb * 8, Bs2 + s * 8);
            }
        }
        __syncthreads();
        for (int ks = 0; ks < 2; ++ks) {
            half8 af[2];
#pragma unroll
            for (int mt = 0; mt < 2; ++mt) {
                int row = mt * 16 + ln;
                int cp = (ks * 4 + q) ^ (row & 7);
                af[mt] = *(const half8*)&As2[row * 64 + cp * 8];
            }
            for (int i = 0; i < NT; ++i) {
                int row = (wv + 4 * i) * 16 + ln;
                int cp = (ks * 4 + q) ^ (row & 7);
                half8 b8 = *(const half8*)&Bs2[row * 64 + cp * 8];
#pragma unroll
                for (int mt = 0; mt < 2; ++mt)
                    acc[mt][i] = __builtin_amdgcn_mfma_f32_16x16x32_f16(af[mt], b8, acc[mt][i], 0, 0, 0);
            }
        }
    }
    float* pslice = part + (size_t)kb * Ctok * 288;
    for (int i = 0; i < NT; ++i) {
        int n = (wv + 4 * i) * 16 + ln;
#pragma unroll
        for (int mt = 0; mt < 2; ++mt)
#pragma unroll
            for (int r = 0; r < 4; ++r) {
                int m = tok0 + mt * 16 + q * 4 + r;
                pslice[(size_t)m * 288 + n] = acc[mt][i][r];
            }
    }
}

// ---------------------------------------------------------------------------
// Fused tail: reduce split-K partials (+bias) -> elu -> fc2(256->32) -> GLU
// -> LN -> softmax -> weighted sum. Block = 8 tokens (32 lanes each).
// ---------------------------------------------------------------------------
__global__ __launch_bounds__(256) void tail_kernel(
    const float* __restrict__ part, const _Float16* __restrict__ stacked,
    const float* __restrict__ sb1, const float* __restrict__ ssb,
    const float* __restrict__ sw2, const float* __restrict__ sb2,
    const float* __restrict__ swg, const float* __restrict__ sbg,
    const float* __restrict__ swf, const float* __restrict__ sbf,
    const float* __restrict__ sgam, const float* __restrict__ sbet,
    float* __restrict__ out, int Ctok, int tok_base)
{
    __shared__ float sw2s[256 * 32];                    // 32 KB
    __shared__ float swgs[1024], swfs[1024];            // 8 KB
    __shared__ float shv[8][257];                       // 8 tokens x 256 (+pad)
    __shared__ float wls[8][33];
    const int t = threadIdx.x;
    const size_t sstr = (size_t)Ctok * 288;
    for (int i = 0; i < 32; ++i) sw2s[t + i * 256] = sw2[t + i * 256];
    for (int i = 0; i < 4; ++i) {
        swgs[t + i * 256] = swg[t + i * 256];
        swfs[t + i * 256] = swf[t + i * 256];
    }
    // stage elu(sum_k part + sb1) for 8 tokens
    for (int i = 0; i < 8; ++i) {
        int idx = t + i * 256;
        int gg = idx >> 8, col = idx & 255;
        size_t base = (size_t)(blockIdx.x * 8 + gg) * 288 + col;
        float z = sb1[col];
#pragma unroll
        for (int s = 0; s < 8; ++s) z += part[s * sstr + base];
        shv[gg][col] = z > 0.f ? z : (expf(z) - 1.f);
    }
    __syncthreads();
    const int g = t >> 5;                               // token group 0..7
    const int j = t & 31;                               // feature index
    const int token = blockIdx.x * 8 + g;               // chunk-local
    // fc2: 256 -> 32
    float p = sb2[j];
    for (int k = 0; k < 256; ++k) p += shv[g][k] * sw2s[k * 32 + j];
    // GLU via width-32 shuffles
    float gacc = sbg[j], uacc = sbf[j];
#pragma unroll 8
    for (int i = 0; i < 32; ++i) {
        float tv = __shfl(p, i, 32);
        gacc += tv * swgs[i * 32 + j];
        uacc += tv * swfs[i * 32 + j];
    }
    float sig = 1.f / (1.f + expf(-gacc));
    // sres = sum_k part[.., 256+j] + ssb
    float sr = ssb[j];
    {
        size_t base = (size_t)token * 288 + 256 + j;
#pragma unroll
        for (int s = 0; s < 8; ++s) sr += part[s * sstr + base];
    }
    float sv = sr + sig * uacc;
    // LayerNorm over 32 lanes
    float s1 = sv, s2 = sv * sv;
    for (int off = 16; off; off >>= 1) {
        s1 += __shfl_xor(s1, off, 32);
        s2 += __shfl_xor(s2, off, 32);
    }
    float mean = s1 * (1.f / 32.f);
    float var = s2 * (1.f / 32.f) - mean * mean;
    float v = (sv - mean) * rsqrtf(var + 1e-5f) * sgam[j] + sbet[j];
    // softmax over 32 lanes
    float mx = v;
    for (int off = 16; off; off >>= 1) mx = fmaxf(mx, __shfl_xor(mx, off, 32));
    float e = expf(v - mx);
    float ssum = e;
    for (int off = 16; off; off >>= 1) ssum += __shfl_xor(ssum, off, 32);
    wls[g][j] = e / ssum;
    __syncthreads();
    // weighted sum over features for the block's 8 tokens
    for (int tk = 0; tk < 8; ++tk) {
        const _Float16* sp = stacked + (size_t)(blockIdx.x * 8 + tk) * FH;
        float a = 0.f;
#pragma unroll
        for (int f = 0; f < 32; ++f) a += (float)sp[f * 256 + t] * wls[tk][f];
        out[(size_t)(tok_base + blockIdx.x * 8 + tk) * 256 + t] = a;
    }
}

// ---------------------------------------------------------------------------
extern "C" void kernel_launch(void* const* d_in, const int* in_sizes, int n_in,
                              void* d_out, int out_size, void* d_ws, size_t ws_size,
                              hipStream_t stream)
{
    (void)in_sizes; (void)n_in; (void)out_size;
    const float* x    = (const float*)d_in[0];
    const float* w1   = (const float*)d_in[1];
    const float* b1   = (const float*)d_in[2];
    const float* w2   = (const float*)d_in[3];
    const float* b2   = (const float*)d_in[4];
    const float* wg   = (const float*)d_in[5];
    const float* bg   = (const float*)d_in[6];
    const float* wf   = (const float*)d_in[7];
    const float* bfp  = (const float*)d_in[8];
    const float* gamma= (const float*)d_in[9];
    const float* beta = (const float*)d_in[10];
    const float* wsk  = (const float*)d_in[11];
    const float* bsk  = (const float*)d_in[12];
    const float* sw1  = (const float*)d_in[13];
    const float* sb1  = (const float*)d_in[14];
    const float* sw2  = (const float*)d_in[15];
    const float* sb2  = (const float*)d_in[16];
    const float* swg  = (const float*)d_in[17];
    const float* sbg  = (const float*)d_in[18];
    const float* swf  = (const float*)d_in[19];
    const float* sbf  = (const float*)d_in[20];
    const float* sgam = (const float*)d_in[21];
    const float* sbet = (const float*)d_in[22];
    const float* ssw  = (const float*)d_in[23];
    const float* ssb  = (const float*)d_in[24];

    // ---- workspace layout, chunk size adaptive to ws_size ----
    // per-token: stacked fp16 (16384 B) + split-K partials 8x288 f32 (9216 B)
    const size_t fixedB = 12582912 + 4718592;            // wt (12 MiB) + wcat (4.5 MiB)
    int C = BT;                                          // tokens per chunk
    while (C > 256) {
        size_t need = fixedB + (size_t)C * 25600;
        if (need <= ws_size) break;
        C >>= 1;
    }
    const int nChunks = BT / C;

    char* ws = (char*)d_ws;
    _Float16* wt      = (_Float16*)ws;                                   // 3 x 2M fp16
    _Float16* wcat    = (_Float16*)(ws + 12582912);                      // 288 x 8192 fp16
    char* p = ws + fixedB;
    _Float16* stacked = (_Float16*)p;            p += (size_t)C * FH * 2;
    float* part       = (float*)p;                                       // 8 x C x 288 f32
    float* out        = (float*)d_out;

    hipLaunchKernelGGL(transpose_w_kernel, dim3(1536), dim3(256), 0, stream, w2, wg, wf, wt);
    hipLaunchKernelGGL(transpose_s_kernel, dim3(640), dim3(256), 0, stream, sw1, ssw, wcat);
    for (int c = 0; c < nChunks; ++c) {
        int tb = c * C;
        hipLaunchKernelGGL(grn_kernel, dim3(C / 32, 32), dim3(256), 0, stream,
                           x, w1, b1, b2, bg, bfp, gamma, beta, wsk, bsk,
                           wt, wt + 2097152, wt + 2 * 2097152, stacked, tb);
        hipLaunchKernelGGL(sel_gemm_kernel, dim3(C / 32, 8), dim3(256), 0, stream,
                           stacked, wcat, part, C);
        hipLaunchKernelGGL(tail_kernel, dim3(C / 8), dim3(256), 0, stream,
                           part, stacked, sb1, ssb, sw2, sb2, swg, sbg, swf, sbf,
                           sgam, sbet, out, C, tb);
    }
}